// Round 10
// baseline (13871.692 us; speedup 1.0000x reference)
//
#include <hip/hip_runtime.h>
#include <hip/hip_bf16.h>
#include <stdint.h>

// ---------------------------------------------------------------------------
// Bidirectional 5-layer LSTM (all-sigmoid), B=16, T=1024, D=1024, U=512.
// R12 = R3 rec (byte-identical protocol, blocks 0..31) + 96 additive
// consumer blocks computing the NEXT layer's xz GEMM from the progressively
// produced (sentinel-valid) y. Failure-ledger constraints honored:
//   - rec path untouched (serialize-then-poll, coalesced h lines, 16x32).
//   - gemm tiles = [8b x 16t] rows, processed in readiness order (middle-out
//     t), gated by a PACER row 32 steps past tile readiness: every rec step
//     ends with a vmcnt(0) drain, so tile lines are >=31 steps settled when
//     staged -> no read-vs-inflight-store racing (R5/R9 law).
//   - y polls are agent-scope atomic loads (R7 L1-staleness lesson).
//   - 128 blocks x 160KB LDS = 1/CU <= 256 CUs: all co-resident, gemm blocks
//     only read -> deadlock-free.
// Workspace 344MB (xz/Wt/Ut double-buffered); falls back to the exact R11
// schedule if ws_size is too small.
// ---------------------------------------------------------------------------

typedef __attribute__((ext_vector_type(8))) short short8;
typedef __attribute__((ext_vector_type(4))) float f32x4;

union U128 { uint4 u; short8 s; };
static __device__ __forceinline__ short8 as_short8(uint4 v) { U128 x; x.u = v; return x.s; }

static __device__ __forceinline__ float sigf(float x) { return 1.0f / (1.0f + __expf(-x)); }

static __device__ __forceinline__ uint32_t f2bfbits(float f) {
  union { float f; uint32_t u; } x; x.f = f;
  return (x.u + 0x7fffu + ((x.u >> 16) & 1u)) >> 16;   // RNE; h in (0,1), no NaN
}
static __device__ __forceinline__ float bflo(uint32_t v) {
  union { uint32_t u; float f; } x; x.u = v << 16; return x.f;
}
static __device__ __forceinline__ float bfhi(uint32_t v) {
  union { uint32_t u; float f; } x; x.u = v & 0xffff0000u; return x.f;
}
static __device__ __forceinline__ bool qok(unsigned long long v) {
  return ((uint32_t)v != 0u) & ((uint32_t)(v >> 32) != 0u);
}

// ---------------- x (fp32) -> bf16 ----------------
__global__ __launch_bounds__(256) void f32_to_bf16_k(const float* __restrict__ in,
                                                     __hip_bfloat16* __restrict__ out,
                                                     int n4) {
  int i = blockIdx.x * 256 + threadIdx.x;
  if (i < n4) {
    float4 v = ((const float4*)in)[i];
    uint32_t lo = f2bfbits(v.x) | (f2bfbits(v.y) << 16);
    uint32_t hi = f2bfbits(v.z) | (f2bfbits(v.w) << 16);
    ((uint2*)out)[i] = make_uint2(lo, hi);
  }
}

// ---------------- [2][R][2048] fp32 -> [2][2048][R] bf16 transpose ----------------
__global__ __launch_bounds__(256) void transpose_bf16_k(const float* __restrict__ in,
                                                        __hip_bfloat16* __restrict__ outp,
                                                        int R) {
  __shared__ float tile[64][65];
  int d = blockIdx.z;
  int k0 = blockIdx.x * 64;
  int c0 = blockIdx.y * 64;
  const float* inb = in + (size_t)d * R * 2048;
  __hip_bfloat16* ob = outp + (size_t)d * 2048 * R;
  int col = threadIdx.x & 63, rr = threadIdx.x >> 6;
#pragma unroll
  for (int i = 0; i < 16; ++i) {
    int r = rr + i * 4;
    tile[r][col] = inb[(size_t)(k0 + r) * 2048 + c0 + col];
  }
  __syncthreads();
#pragma unroll
  for (int i = 0; i < 16; ++i) {
    int r = rr + i * 4;
    ob[(size_t)(c0 + r) * R + k0 + col] = __float2bfloat16(tile[col][r]);
  }
}

// ---------------- standalone xz GEMM (layer 0 only / fallback path) ----------------
// Output layout: xz[dir][swg(16)][t(1024)][q(4)][b(16)][j(32)]  (4KB per (dir,swg,t))
__global__ __launch_bounds__(256) void gemm_xz_k(const __hip_bfloat16* __restrict__ y,
                                                 const __hip_bfloat16* __restrict__ Wt,
                                                 const float* __restrict__ bias,
                                                 __hip_bfloat16* __restrict__ xz) {
  __shared__ uint4 Asl[8 * 2 * 64];
  __shared__ uint4 Bsl[8 * 2 * 64];
  int m0 = blockIdx.x * 128;
  int dir = blockIdx.y >> 4;
  int n0 = (blockIdx.y & 15) * 128;
  int tid = threadIdx.x, lane = tid & 63, wv = tid >> 6;
  int wm = wv & 1, wn = wv >> 1;
  const __hip_bfloat16* Wd = Wt + (size_t)dir * 2048 * 1024;
  f32x4 acc[4][4] = {};
  for (int kb = 0; kb < 1024; kb += 64) {
    __syncthreads();
#pragma unroll
    for (int i = 0; i < 4; ++i) {
      int slot = i * 256 + tid;
      int ln = slot & 63, kc = (slot >> 6) & 1, mt = slot >> 7;
      int row = mt * 16 + (ln & 15);
      int kk = kc * 32 + (ln >> 4) * 8;
      Asl[slot] = *(const uint4*)(y + (size_t)(m0 + row) * 1024 + kb + kk);
      Bsl[slot] = *(const uint4*)(Wd + (size_t)(n0 + row) * 1024 + kb + kk);
    }
    __syncthreads();
#pragma unroll
    for (int kc = 0; kc < 2; ++kc) {
      short8 af[4], bf[4];
#pragma unroll
      for (int i = 0; i < 4; ++i) {
        af[i] = as_short8(Asl[((wm * 4 + i) * 2 + kc) * 64 + lane]);
        bf[i] = as_short8(Bsl[((wn * 4 + i) * 2 + kc) * 64 + lane]);
      }
#pragma unroll
      for (int i = 0; i < 4; ++i)
#pragma unroll
        for (int j = 0; j < 4; ++j)
          acc[i][j] = __builtin_amdgcn_mfma_f32_16x16x32_bf16(af[i], bf[j], acc[i][j], 0, 0, 0);
    }
  }
  int cq = lane >> 4, cn = lane & 15;
#pragma unroll
  for (int i = 0; i < 4; ++i)
#pragma unroll
    for (int j = 0; j < 4; ++j) {
      int n_g = n0 + (wn * 4 + j) * 16 + cn;
      int q = n_g >> 9, u = n_g & 511, swg = u >> 5, jj = u & 31;
      float bv = bias[dir * 2048 + n_g];
#pragma unroll
      for (int r = 0; r < 4; ++r) {
        int m = m0 + (wm * 4 + i) * 16 + cq * 4 + r;
        int bb = m >> 10, t = m & 1023;
        size_t addr = (((size_t)(dir * 16 + swg) * 1024 + t) * 2048) + (q * 16 + bb) * 32 + jj;
        xz[addr] = __float2bfloat16(acc[i][j][r] + bv);
      }
    }
}

// ---------------- fused: rec(l) [blocks 0..31] + gemm(l+1) [blocks 32..127] ----------------
__global__ __launch_bounds__(256) void lstm_rec_k(const __hip_bfloat16* __restrict__ Ut,   // layer l [2][2048][512]
                                                  const __hip_bfloat16* __restrict__ xz,   // layer l xz
                                                  __hip_bfloat16* __restrict__ ynext,      // layer l output, pre-zeroed
                                                  float* __restrict__ outf,                // last layer or null
                                                  const __hip_bfloat16* __restrict__ Wtn,  // layer l+1 Wt or null
                                                  const float* __restrict__ biasn,         // layer l+1 bias or null
                                                  __hip_bfloat16* __restrict__ xznext) {   // layer l+1 xz or null
  extern __shared__ char smem[];
  int tid = threadIdx.x, lane = tid & 63, wv = tid >> 6;

  if (blockIdx.x < 32) {
    // ================= rec role: byte-identical R3 =================
    uint4* uh = (uint4*)smem;                                 // 8192 x 16B
    __hip_bfloat16* hbuf = (__hip_bfloat16*)(smem + 131072);  // [16][520]
    float* zbuf = (float*)(smem + 147712);                    // [16][128]
    __hip_bfloat16* xbuf = (__hip_bfloat16*)(smem + 155904);  // [2048]
    int dir = blockIdx.x & 1;
    int swg = blockIdx.x >> 1;
    int u0 = swg * 32;
    int quad = lane >> 4, l15 = lane & 15;
    const __hip_bfloat16* Ud = Ut + (size_t)dir * 2048 * 512;

#pragma unroll 4
    for (int i = 0; i < 32; ++i) {
      int slot = i * 256 + tid;
      int ls = slot & 63, kc = (slot >> 6) & 15, nt = slot >> 10;
      int n_g = (nt >> 1) * 512 + u0 + (nt & 1) * 16 + (ls & 15);
      int k = kc * 32 + (ls >> 4) * 8;
      uh[slot] = *(const uint4*)(Ud + (size_t)n_g * 512 + k);
    }
    __syncthreads();

    int nt0 = wv * 2, nt1 = wv * 2 + 1;
    int pb = tid >> 4, pj = (tid & 15) * 2;
    float c0 = 0.f, c1 = 0.f;

    int t0 = dir ? 1023 : 0;
    const uint4* xp0 = (const uint4*)(xz + ((size_t)(dir * 16 + swg) * 1024 + t0) * 2048) + tid;
    uint4 xcur = *xp0;

    for (int s = 0; s < 1024; ++s) {
      int t = dir ? (1023 - s) : s;
      uint4 xnxt;
      if (s < 1023) {
        int tn = dir ? (1022 - s) : (s + 1);
        xnxt = *((const uint4*)(xz + ((size_t)(dir * 16 + swg) * 1024 + tn) * 2048) + tid);
      }
      f32x4 z0 = {}, z1 = {};
      if (s > 0) {
        int tprev = dir ? (t + 1) : (t - 1);
        unsigned long long hv[8];
        const unsigned long long* gp[8];
#pragma unroll
        for (int i = 0; i < 4; ++i) {
          int v = i * 2048 + tid * 8;
          int bb = v >> 9, col = v & 511;
          const unsigned long long* g =
              (const unsigned long long*)(ynext + ((size_t)bb * 1024 + tprev) * 1024 + dir * 512 + col);
          gp[2 * i] = g;
          gp[2 * i + 1] = g + 1;
        }
#pragma unroll
        for (int i = 0; i < 8; ++i)
          hv[i] = __hip_atomic_load(gp[i], __ATOMIC_RELAXED, __HIP_MEMORY_SCOPE_AGENT);
        for (;;) {
          bool ok = true;
#pragma unroll
          for (int i = 0; i < 8; ++i)
            ok &= ((uint32_t)hv[i] != 0u) && ((uint32_t)(hv[i] >> 32) != 0u);
          if (ok) break;
#pragma unroll
          for (int i = 0; i < 8; ++i)
            if (((uint32_t)hv[i] == 0u) || ((uint32_t)(hv[i] >> 32) == 0u))
              hv[i] = __hip_atomic_load(gp[i], __ATOMIC_RELAXED, __HIP_MEMORY_SCOPE_AGENT);
        }
#pragma unroll
        for (int i = 0; i < 4; ++i) {
          int v = i * 2048 + tid * 8;
          int bb = v >> 9, col = v & 511;
          unsigned long long* lp = (unsigned long long*)(hbuf + bb * 520 + col);
          lp[0] = hv[2 * i];
          lp[1] = hv[2 * i + 1];
        }
        __syncthreads();
#pragma unroll
        for (int kc = 0; kc < 16; ++kc) {
          short8 afrag = *(const short8*)(hbuf + l15 * 520 + kc * 32 + quad * 8);
          z0 = __builtin_amdgcn_mfma_f32_16x16x32_bf16(afrag, as_short8(uh[(nt0 * 16 + kc) * 64 + lane]), z0, 0, 0, 0);
          z1 = __builtin_amdgcn_mfma_f32_16x16x32_bf16(afrag, as_short8(uh[(nt1 * 16 + kc) * 64 + lane]), z1, 0, 0, 0);
        }
      }
#pragma unroll
      for (int r = 0; r < 4; ++r) {
        int m = quad * 4 + r;
        zbuf[m * 128 + nt0 * 16 + l15] = z0[r];
        zbuf[m * 128 + nt1 * 16 + l15] = z1[r];
      }
      *(uint4*)(xbuf + tid * 8) = xcur;
      __syncthreads();
      const float* zb = zbuf + pb * 128;
      uint32_t xi = *(const uint32_t*)(xbuf + (0 * 16 + pb) * 32 + pj);
      uint32_t xf = *(const uint32_t*)(xbuf + (1 * 16 + pb) * 32 + pj);
      uint32_t xg = *(const uint32_t*)(xbuf + (2 * 16 + pb) * 32 + pj);
      uint32_t xo = *(const uint32_t*)(xbuf + (3 * 16 + pb) * 32 + pj);
      float i0 = sigf(zb[pj] + bflo(xi)),      i1 = sigf(zb[pj + 1] + bfhi(xi));
      float f0 = sigf(zb[32 + pj] + bflo(xf)), f1 = sigf(zb[32 + pj + 1] + bfhi(xf));
      float g0 = sigf(zb[64 + pj] + bflo(xg)), g1 = sigf(zb[64 + pj + 1] + bfhi(xg));
      float o0 = sigf(zb[96 + pj] + bflo(xo)), o1 = sigf(zb[96 + pj + 1] + bfhi(xo));
      c0 = f0 * c0 + i0 * g0;
      c1 = f1 * c1 + i1 * g1;
      float h0 = o0 * sigf(c0);
      float h1 = o1 * sigf(c1);
      size_t oidx = ((size_t)pb * 1024 + t) * 1024 + dir * 512 + u0 + pj;
      uint32_t ha = f2bfbits(h0); ha += (ha == 0u);
      uint32_t hb = f2bfbits(h1); hb += (hb == 0u);
      uint32_t hp = ha | (hb << 16);
      __hip_atomic_store((uint32_t*)(ynext + oidx), hp, __ATOMIC_RELAXED, __HIP_MEMORY_SCOPE_AGENT);
      if (outf) { outf[oidx] = h0; outf[oidx + 1] = h1; }
      __syncthreads();   // vmcnt(0) drain: h visible before next poll (load-bearing)
      xcur = xnxt;
    }
    return;
  }

  // ================= gemm role: xz for layer l+1 =================
  if (!xznext) return;
  uint4* Asl = (uint4*)smem;          // 1024 x 16B
  uint4* Bsl = ((uint4*)smem) + 1024; // 1024 x 16B
  int gb = blockIdx.x - 32;           // 0..95
  int wm = wv & 1, wn = wv >> 1;
  // tiles: g = k*64 + inner; k -> t-chunk c (middle-out readiness order);
  // inner = dir*32 + ngi*2 + bg. Tile rows = [bg*8..+8) batches x [c*16..+16) t.
  for (int g = gb; g < 4096; g += 96) {
    int kq = g >> 6, inner = g & 63;
    int c = (kq & 1) ? (31 - (kq >> 1)) : (32 + (kq >> 1));
    int tt0 = c * 16;
    int bg = inner & 1, ngi = (inner >> 1) & 15, gdir = inner >> 5;
    int n0 = ngi * 128;
    const __hip_bfloat16* Wd = Wtn + (size_t)gdir * 2048 * 1024;
    // PACER: rows of this tile complete at rec step r = max(t0+15, 1023-t0).
    // Wait for the fwd-half word of a row finishing 32 steps later: every rec
    // step ends with a vmcnt(0) drain, so when the pacer is visible, this
    // tile's lines have been settled in the LLC for >=31 steps -> the A-polls
    // below never race in-flight stores (R5/R9 law).
    {
      int rr = (tt0 + 15 > 1023 - tt0) ? (tt0 + 15) : (1023 - tt0);
      int tp = rr + 32; if (tp > 1023) tp = 1023;
      const uint32_t* pp = (const uint32_t*)(ynext + ((size_t)(bg * 8) * 1024 + tp) * 1024);
      while (__hip_atomic_load(pp, __ATOMIC_RELAXED, __HIP_MEMORY_SCOPE_AGENT) == 0u)
        __builtin_amdgcn_s_sleep(32);
    }
    f32x4 acc[4][4] = {};
    for (int kb = 0; kb < 1024; kb += 64) {
      __syncthreads();
#pragma unroll
      for (int i = 0; i < 4; ++i) {
        int slot = i * 256 + tid;
        int ln = slot & 63, kc = (slot >> 6) & 1, mt = slot >> 7;
        int row = mt * 16 + (ln & 15);
        int kcol = kc * 32 + (ln >> 4) * 8;
        int bb = bg * 8 + (row >> 4), tt = tt0 + (row & 15);
        const unsigned long long* ap =
            (const unsigned long long*)(ynext + ((size_t)bb * 1024 + tt) * 1024 + kb + kcol);
        unsigned long long a0 = __hip_atomic_load(ap, __ATOMIC_RELAXED, __HIP_MEMORY_SCOPE_AGENT);
        unsigned long long a1 = __hip_atomic_load(ap + 1, __ATOMIC_RELAXED, __HIP_MEMORY_SCOPE_AGENT);
        while (!(qok(a0) & qok(a1))) {   // safety net; pacer makes this ~never spin
          __builtin_amdgcn_s_sleep(8);
          if (!qok(a0)) a0 = __hip_atomic_load(ap, __ATOMIC_RELAXED, __HIP_MEMORY_SCOPE_AGENT);
          if (!qok(a1)) a1 = __hip_atomic_load(ap + 1, __ATOMIC_RELAXED, __HIP_MEMORY_SCOPE_AGENT);
        }
        unsigned long long* asl = (unsigned long long*)&Asl[slot];
        asl[0] = a0; asl[1] = a1;
        Bsl[slot] = *(const uint4*)(Wd + (size_t)(n0 + row) * 1024 + kb + kcol);
      }
      __syncthreads();
#pragma unroll
      for (int kc = 0; kc < 2; ++kc) {
        short8 af[4], bf[4];
#pragma unroll
        for (int i = 0; i < 4; ++i) {
          af[i] = as_short8(Asl[((wm * 4 + i) * 2 + kc) * 64 + lane]);
          bf[i] = as_short8(Bsl[((wn * 4 + i) * 2 + kc) * 64 + lane]);
        }
#pragma unroll
        for (int i = 0; i < 4; ++i)
#pragma unroll
          for (int j = 0; j < 4; ++j)
            acc[i][j] = __builtin_amdgcn_mfma_f32_16x16x32_bf16(af[i], bf[j], acc[i][j], 0, 0, 0);
      }
    }
    int cq = lane >> 4, cn = lane & 15;
#pragma unroll
    for (int i = 0; i < 4; ++i)
#pragma unroll
      for (int j = 0; j < 4; ++j) {
        int n_g = n0 + (wn * 4 + j) * 16 + cn;
        int q = n_g >> 9, uu = n_g & 511, sw = uu >> 5, jj = uu & 31;
        float bv = biasn[gdir * 2048 + n_g];
#pragma unroll
        for (int r = 0; r < 4; ++r) {
          int ml = (wm * 4 + i) * 16 + cq * 4 + r;
          int bb = bg * 8 + (ml >> 4), tt = tt0 + (ml & 15);
          size_t addr = (((size_t)(gdir * 16 + sw) * 1024 + tt) * 2048) + (q * 16 + bb) * 32 + jj;
          xznext[addr] = __float2bfloat16(acc[i][j][r] + bv);
        }
      }
  }
}

// ---------------------------------------------------------------------------
extern "C" void kernel_launch(void* const* d_in, const int* in_sizes, int n_in,
                              void* d_out, int out_size, void* d_ws, size_t ws_size,
                              hipStream_t stream) {
  const float* x  = (const float*)d_in[0];   // [16][1024][1024]
  const float* W  = (const float*)d_in[1];   // [5][2][1024][2048]
  const float* Uh = (const float*)d_in[2];   // [5][2][512][2048]
  const float* b  = (const float*)d_in[3];   // [5][2][2048]

  char* ws = (char*)d_ws;
  size_t off = 0;
  __hip_bfloat16* yA  = (__hip_bfloat16*)(ws + off); off += (size_t)16 * 1024 * 1024 * 2;
  __hip_bfloat16* yB  = (__hip_bfloat16*)(ws + off); off += (size_t)16 * 1024 * 1024 * 2;
  __hip_bfloat16* xzA = (__hip_bfloat16*)(ws + off); off += (size_t)2 * 16 * 1024 * 2048 * 2;
  __hip_bfloat16* WtA = (__hip_bfloat16*)(ws + off); off += (size_t)2 * 2048 * 1024 * 2;
  __hip_bfloat16* UtA = (__hip_bfloat16*)(ws + off); off += (size_t)2 * 2048 * 512 * 2;
  // extended buffers (fused path only):
  __hip_bfloat16* xzB = (__hip_bfloat16*)(ws + off); off += (size_t)2 * 16 * 1024 * 2048 * 2;
  __hip_bfloat16* WtB = (__hip_bfloat16*)(ws + off); off += (size_t)2 * 2048 * 1024 * 2;
  __hip_bfloat16* UtB = (__hip_bfloat16*)(ws + off); off += (size_t)2 * 2048 * 512 * 2;
  const bool fuse = (ws_size >= off);

  f32_to_bf16_k<<<dim3(16384), dim3(256), 0, stream>>>(x, yA, 4194304);
  hipFuncSetAttribute(reinterpret_cast<const void*>(lstm_rec_k),
                      hipFuncAttributeMaxDynamicSharedMemorySize, 160000);

  if (!fuse) {
    // -------- fallback: exact R11 schedule --------
    for (int l = 0; l < 5; ++l) {
      transpose_bf16_k<<<dim3(16, 32, 2), dim3(256), 0, stream>>>(W + (size_t)l * 2 * 1024 * 2048, WtA, 1024);
      transpose_bf16_k<<<dim3(8, 32, 2),  dim3(256), 0, stream>>>(Uh + (size_t)l * 2 * 512 * 2048, UtA, 512);
      __hip_bfloat16* ycur = (l & 1) ? yB : yA;
      __hip_bfloat16* ynxt = (l & 1) ? yA : yB;
      hipMemsetAsync(ynxt, 0, (size_t)16 * 1024 * 1024 * 2, stream);
      gemm_xz_k<<<dim3(128, 32), dim3(256), 0, stream>>>(ycur, WtA, b + (size_t)l * 2 * 2048, xzA);
      lstm_rec_k<<<dim3(32), dim3(256), 160000, stream>>>(
          UtA, xzA, ynxt, (l == 4) ? (float*)d_out : nullptr, nullptr, nullptr, nullptr);
    }
    return;
  }

  // -------- fused pipeline --------
  __hip_bfloat16* Wtb[2] = {WtA, WtB};
  __hip_bfloat16* Utb[2] = {UtA, UtB};
  __hip_bfloat16* xzb[2] = {xzA, xzB};

  // prologue: layer-0 weights + xz (nothing to hide under yet)
  transpose_bf16_k<<<dim3(16, 32, 2), dim3(256), 0, stream>>>(W, Wtb[0], 1024);
  transpose_bf16_k<<<dim3(8, 32, 2),  dim3(256), 0, stream>>>(Uh, Utb[0], 512);
  hipMemsetAsync(yB, 0, (size_t)16 * 1024 * 1024 * 2, stream);   // rec(0) target
  gemm_xz_k<<<dim3(128, 32), dim3(256), 0, stream>>>(yA, Wtb[0], b, xzb[0]);

  for (int l = 0; l < 5; ++l) {
    __hip_bfloat16* ycur = (l & 1) ? yB : yA;
    __hip_bfloat16* ynxt = (l & 1) ? yA : yB;
    __hip_bfloat16* xzc  = xzb[l & 1];
    __hip_bfloat16* xzn  = xzb[(l + 1) & 1];
    if (l < 4)  // Wt for layer l+1, ready before fused(l)'s gemm role
      transpose_bf16_k<<<dim3(16, 32, 2), dim3(256), 0, stream>>>(
          W + (size_t)(l + 1) * 2 * 1024 * 2048, Wtb[(l + 1) & 1], 1024);
    int grid = (l < 4) ? 128 : 32;
    lstm_rec_k<<<dim3(grid), dim3(256), 160000, stream>>>(
        Utb[l & 1], xzc, ynxt, (l == 4) ? (float*)d_out : nullptr,
        (l < 4) ? Wtb[(l + 1) & 1] : nullptr,
        (l < 4) ? (b + (size_t)(l + 1) * 2 * 2048) : nullptr,
        (l < 4) ? xzn : nullptr);
    if (l < 4) {
      transpose_bf16_k<<<dim3(8, 32, 2), dim3(256), 0, stream>>>(
          Uh + (size_t)(l + 1) * 2 * 512 * 2048, Utb[(l + 1) & 1], 512);
      // zero rec(l+1)'s target (= ycur, now fully consumed by gemm(l)/rec(l))
      hipMemsetAsync(ycur, 0, (size_t)16 * 1024 * 1024 * 2, stream);
    }
  }
}